// Round 1
// baseline (62.460 us; speedup 1.0000x reference)
//
#include <hip/hip_runtime.h>

namespace {
constexpr int B_ = 4;
constexpr int N_ = 240 * 320;   // 76800 pixels per image (C == 1)
constexpr int M_ = 256;         // bins
constexpr int TILE = 256;       // pixels staged per LDS tile
constexpr int NTILES = N_ / TILE;  // 300
constexpr int NCHUNK = 75;      // main-kernel blocks per batch (300 tiles / 4 tiles each)
constexpr int MAXBLK = 64;      // max-kernel blocks per batch

// ws layout in 4-byte words:
//   [WS_MAX,    WS_MAX+B_)          uint-bits of per-batch max  (atomicMax)
//   [WS_BINMIN, WS_BINMIN+B_*M_)    uint-bits of per-(batch,bin) min sq-dist (atomicMin)
//   [WS_PART,   WS_PART+B_*NCHUNK)  float per-(batch,chunk) partial t2b sums
constexpr int WS_MAX = 0;
constexpr int WS_BINMIN = B_;
constexpr int WS_PART = B_ + B_ * M_;
}  // namespace

__global__ void ws_init_kernel(unsigned* __restrict__ ws) {
  int tid = threadIdx.x + blockIdx.x * blockDim.x;
  if (tid < B_) ws[WS_MAX + tid] = 0u;                     // positive floats: 0 bits = 0.0f
  if (tid < B_ * M_) ws[WS_BINMIN + tid] = 0x7f800000u;    // +inf
}

__global__ void img_max_kernel(const float* __restrict__ target,
                               unsigned* __restrict__ ws) {
  int b = blockIdx.x / MAXBLK;
  int blk = blockIdx.x % MAXBLK;
  int tid = threadIdx.x;
  const float4* img4 = reinterpret_cast<const float4*>(target + b * N_);
  float m = 0.f;
  const int stride = MAXBLK * 256;
  for (int i = blk * 256 + tid; i < N_ / 4; i += stride) {
    float4 v = img4[i];
    m = fmaxf(fmaxf(m, v.x), fmaxf(fmaxf(v.y, v.z), v.w));
  }
  __shared__ float red[256];
  red[tid] = m;
  __syncthreads();
#pragma unroll
  for (int s = 128; s > 0; s >>= 1) {
    if (tid < s) red[tid] = fmaxf(red[tid], red[tid + s]);
    __syncthreads();
  }
  if (tid == 0) atomicMax(&ws[WS_MAX + b], __float_as_uint(red[0]));
}

__global__ void chamfer_main_kernel(const float* __restrict__ target,
                                    const float* __restrict__ bins,
                                    unsigned* __restrict__ ws) {
  const int b = blockIdx.x / NCHUNK;
  const int chunk = blockIdx.x % NCHUNK;
  const int tid = threadIdx.x;

  __shared__ __align__(16) float lds_bins[M_];
  __shared__ __align__(16) float lds_t[TILE];
  __shared__ float red[256];

  const float maxv = __uint_as_float(ws[WS_MAX + b]);

  // normalized bins -> LDS (exact fp32 division, matching reference)
  lds_bins[tid] = bins[b * M_ + tid] / maxv;
  __syncthreads();

  const float c_j = lds_bins[tid];        // this thread's bin (phase B)
  float binmin_j = 3.4e38f;               // min over this block's pixels for bin j
  float sum_t2b = 0.f;                    // sum of per-pixel min over bins

  const float* img = target + b * N_;
  const float4* bins4 = reinterpret_cast<const float4*>(lds_bins);
  const float4* t4 = reinterpret_cast<const float4*>(lds_t);

  for (int tile = chunk; tile < NTILES; tile += NCHUNK) {
    __syncthreads();  // protect lds_t from previous iteration's readers
    const float t_i = img[tile * TILE + tid] / maxv;
    lds_t[tid] = t_i;
    __syncthreads();

    // Phase A: thread = pixel; min over all 256 bins (LDS broadcast reads)
    float tmin = 3.4e38f;
#pragma unroll 8
    for (int m4 = 0; m4 < M_ / 4; ++m4) {
      float4 c = bins4[m4];
      float d0 = c.x - t_i; d0 *= d0;
      float d1 = c.y - t_i; d1 *= d1;
      float d2 = c.z - t_i; d2 *= d2;
      float d3 = c.w - t_i; d3 *= d3;
      tmin = fminf(tmin, fminf(fminf(d0, d1), fminf(d2, d3)));
    }
    sum_t2b += tmin;

    // Phase B: thread = bin; min over the 256 staged pixels (LDS broadcast reads)
#pragma unroll 8
    for (int p4 = 0; p4 < TILE / 4; ++p4) {
      float4 t = t4[p4];
      float d0 = c_j - t.x; d0 *= d0;
      float d1 = c_j - t.y; d1 *= d1;
      float d2 = c_j - t.z; d2 *= d2;
      float d3 = c_j - t.w; d3 *= d3;
      binmin_j = fminf(binmin_j, fminf(fminf(d0, d1), fminf(d2, d3)));
    }
  }

  // block reduce sum_t2b (fixed order -> deterministic)
  red[tid] = sum_t2b;
  __syncthreads();
#pragma unroll
  for (int s = 128; s > 0; s >>= 1) {
    if (tid < s) red[tid] += red[tid + s];
    __syncthreads();
  }
  if (tid == 0) {
    reinterpret_cast<float*>(ws)[WS_PART + b * NCHUNK + chunk] = red[0];
  }

  // per-bin min across blocks: integer atomicMin on positive-float bits
  // (commutative & exact -> deterministic)
  atomicMin(&ws[WS_BINMIN + b * M_ + tid], __float_as_uint(binmin_j));
}

__global__ void chamfer_final_kernel(const unsigned* __restrict__ ws,
                                     float* __restrict__ out) {
  const int tid = threadIdx.x;
  __shared__ float red[256];

  // bins -> nearest pixel: sum all B_*M_ mins
  float acc_b2t = 0.f;
#pragma unroll
  for (int b = 0; b < B_; ++b) {
    acc_b2t += __uint_as_float(ws[WS_BINMIN + b * M_ + tid]);
  }

  // pixels -> nearest bin: sum the B_*NCHUNK partials (fixed order)
  float acc_t2b = 0.f;
  for (int i = tid; i < B_ * NCHUNK; i += 256) {
    acc_t2b += reinterpret_cast<const float*>(ws)[WS_PART + i];
  }

  float v = acc_b2t / (float)M_ + acc_t2b / (float)N_;
  red[tid] = v;
  __syncthreads();
#pragma unroll
  for (int s = 128; s > 0; s >>= 1) {
    if (tid < s) red[tid] += red[tid + s];
    __syncthreads();
  }
  if (tid == 0) {
    out[0] = red[0] / (float)B_ * 10.0f;
  }
}

extern "C" void kernel_launch(void* const* d_in, const int* in_sizes, int n_in,
                              void* d_out, int out_size, void* d_ws, size_t ws_size,
                              hipStream_t stream) {
  (void)in_sizes; (void)n_in; (void)out_size; (void)ws_size;
  const float* target = reinterpret_cast<const float*>(d_in[0]);
  const float* bins = reinterpret_cast<const float*>(d_in[1]);
  unsigned* ws = reinterpret_cast<unsigned*>(d_ws);
  float* out = reinterpret_cast<float*>(d_out);

  ws_init_kernel<<<4, 256, 0, stream>>>(ws);
  img_max_kernel<<<B_ * MAXBLK, 256, 0, stream>>>(target, ws);
  chamfer_main_kernel<<<B_ * NCHUNK, 256, 0, stream>>>(target, bins, ws);
  chamfer_final_kernel<<<1, 256, 0, stream>>>(ws, out);
}

// Round 2
// 25.804 us; speedup vs baseline: 2.4205x; 2.4205x over previous
//
#include <hip/hip_runtime.h>

namespace {
constexpr int B_ = 4;
constexpr int N_ = 240 * 320;      // 76800 pixels per image (C == 1)
constexpr int M_ = 256;            // bins
constexpr int PIX_BLK = 1024;      // pixels per main-kernel block
constexpr int NCHUNK = N_ / PIX_BLK;  // 75 blocks per batch

// ws layout in 4-byte words:
//   [WS_MAX,    WS_MAX+4)       float per-batch max
//   [WS_BINMIN, +4*256)         uint-bits of per-(batch,bin) min sq-dist (atomicMin)
//   [WS_PART,   +4*75)          float per-(batch,chunk) partial t2b sums
constexpr int WS_MAX = 0;
constexpr int WS_BINMIN = 4;
constexpr int WS_PART = 4 + B_ * M_;
}  // namespace

// One block per batch: computes per-image max (no atomics) and re-inits the
// per-bin min slots for this launch (deterministic across replays).
__global__ __launch_bounds__(1024) void img_max_kernel(const float* __restrict__ target,
                                                       unsigned* __restrict__ ws) {
  const int b = blockIdx.x;
  const int tid = threadIdx.x;
  const float4* img4 = reinterpret_cast<const float4*>(target + b * N_);
  float m = 0.f;
  for (int i = tid; i < N_ / 4; i += 1024) {
    float4 v = img4[i];
    m = fmaxf(fmaxf(m, v.x), fmaxf(fmaxf(v.y, v.z), v.w));
  }
#pragma unroll
  for (int o = 32; o > 0; o >>= 1) m = fmaxf(m, __shfl_down(m, o));
  __shared__ float lds[16];
  if ((tid & 63) == 0) lds[tid >> 6] = m;
  __syncthreads();
  if (tid == 0) {
    float mm = lds[0];
#pragma unroll
    for (int w = 1; w < 16; ++w) mm = fmaxf(mm, lds[w]);
    reinterpret_cast<float*>(ws)[WS_MAX + b] = mm;
  }
  if (tid < M_) ws[WS_BINMIN + b * M_ + tid] = 0x7f800000u;  // +inf
}

__global__ __launch_bounds__(1024) void chamfer_main_kernel(const float* __restrict__ target,
                                                            const float* __restrict__ bins,
                                                            unsigned* __restrict__ ws) {
  const int b = blockIdx.x / NCHUNK;
  const int chunk = blockIdx.x % NCHUNK;
  const int tid = threadIdx.x;

  __shared__ __align__(16) float lds_bins[M_];
  __shared__ __align__(16) float lds_t[PIX_BLK];
  __shared__ float lds_red[PIX_BLK];
  __shared__ float lds_sum[16];

  const float maxv = reinterpret_cast<const float*>(ws)[WS_MAX + b];

  if (tid < M_) lds_bins[tid] = bins[b * M_ + tid] / maxv;  // exact fp32 div
  const float t_i = target[b * N_ + chunk * PIX_BLK + tid] / maxv;
  lds_t[tid] = t_i;
  __syncthreads();

  // ---- Phase A: thread = pixel; min over 256 bins (LDS broadcast reads) ----
  const float4* bins4 = reinterpret_cast<const float4*>(lds_bins);
  float a0 = 3.4e38f, a1 = 3.4e38f;  // two accumulators for ILP
#pragma unroll 8
  for (int m4 = 0; m4 < M_ / 4; m4 += 2) {
    float4 c0 = bins4[m4];
    float4 c1 = bins4[m4 + 1];
    float d0 = c0.x - t_i; d0 *= d0;
    float d1 = c0.y - t_i; d1 *= d1;
    float d2 = c0.z - t_i; d2 *= d2;
    float d3 = c0.w - t_i; d3 *= d3;
    a0 = fminf(a0, fminf(fminf(d0, d1), fminf(d2, d3)));
    float e0 = c1.x - t_i; e0 *= e0;
    float e1 = c1.y - t_i; e1 *= e1;
    float e2 = c1.z - t_i; e2 *= e2;
    float e3 = c1.w - t_i; e3 *= e3;
    a1 = fminf(a1, fminf(fminf(e0, e1), fminf(e2, e3)));
  }
  float tmin = fminf(a0, a1);

  // ---- Phase B: thread (q = tid>>8, j = tid&255) = bin j over quarter-tile q ----
  const int q = tid >> 8;
  const int j = tid & 255;
  const float c_j = lds_bins[j];
  const float4* t4 = reinterpret_cast<const float4*>(lds_t + q * 256);
  float b0 = 3.4e38f, b1 = 3.4e38f;
#pragma unroll 8
  for (int p4 = 0; p4 < 64; p4 += 2) {
    float4 u0 = t4[p4];
    float4 u1 = t4[p4 + 1];
    float d0 = c_j - u0.x; d0 *= d0;
    float d1 = c_j - u0.y; d1 *= d1;
    float d2 = c_j - u0.z; d2 *= d2;
    float d3 = c_j - u0.w; d3 *= d3;
    b0 = fminf(b0, fminf(fminf(d0, d1), fminf(d2, d3)));
    float e0 = c_j - u1.x; e0 *= e0;
    float e1 = c_j - u1.y; e1 *= e1;
    float e2 = c_j - u1.z; e2 *= e2;
    float e3 = c_j - u1.w; e3 *= e3;
    b1 = fminf(b1, fminf(fminf(e0, e1), fminf(e2, e3)));
  }
  float binmin = fminf(b0, b1);

  // ---- Reductions ----
  // t2b: wave shuffle reduce (fixed order -> deterministic), then 16 partials
  float s = tmin;
#pragma unroll
  for (int o = 32; o > 0; o >>= 1) s += __shfl_down(s, o);
  if ((tid & 63) == 0) lds_sum[tid >> 6] = s;
  // b2t: stash per-quarter bin mins
  lds_red[tid] = binmin;  // index q*256 + j == tid
  __syncthreads();

  if (tid == 0) {
    float tot = lds_sum[0];
#pragma unroll
    for (int w = 1; w < 16; ++w) tot += lds_sum[w];
    reinterpret_cast<float*>(ws)[WS_PART + b * NCHUNK + chunk] = tot;
  }
  if (tid < M_) {
    float m4v = fminf(fminf(lds_red[tid], lds_red[256 + tid]),
                      fminf(lds_red[512 + tid], lds_red[768 + tid]));
    // integer atomicMin on positive-float bits: commutative & exact -> deterministic
    atomicMin(&ws[WS_BINMIN + b * M_ + tid], __float_as_uint(m4v));
  }
}

__global__ void chamfer_final_kernel(const unsigned* __restrict__ ws,
                                     float* __restrict__ out) {
  const int tid = threadIdx.x;

  float acc_b = 0.f;
#pragma unroll
  for (int b = 0; b < B_; ++b) acc_b += __uint_as_float(ws[WS_BINMIN + b * M_ + tid]);

  float acc_t = 0.f;
  for (int i = tid; i < B_ * NCHUNK; i += 256)
    acc_t += reinterpret_cast<const float*>(ws)[WS_PART + i];

  float v = acc_b / (float)M_ + acc_t / (float)N_;
#pragma unroll
  for (int o = 32; o > 0; o >>= 1) v += __shfl_down(v, o);
  __shared__ float lds[4];
  if ((tid & 63) == 0) lds[tid >> 6] = v;
  __syncthreads();
  if (tid == 0) out[0] = (lds[0] + lds[1] + lds[2] + lds[3]) * 0.25f * 10.0f;
}

extern "C" void kernel_launch(void* const* d_in, const int* in_sizes, int n_in,
                              void* d_out, int out_size, void* d_ws, size_t ws_size,
                              hipStream_t stream) {
  (void)in_sizes; (void)n_in; (void)out_size; (void)ws_size;
  const float* target = reinterpret_cast<const float*>(d_in[0]);
  const float* bins = reinterpret_cast<const float*>(d_in[1]);
  unsigned* ws = reinterpret_cast<unsigned*>(d_ws);
  float* out = reinterpret_cast<float*>(d_out);

  img_max_kernel<<<B_, 1024, 0, stream>>>(target, ws);
  chamfer_main_kernel<<<B_ * NCHUNK, 1024, 0, stream>>>(target, bins, ws);
  chamfer_final_kernel<<<1, 256, 0, stream>>>(ws, out);
}